// Round 2
// baseline (357.249 us; speedup 1.0000x reference)
//
#include <hip/hip_runtime.h>

// Advect: minmod-limited flux stencil along last axis.
// L = 8192 (ghost-padded), OUT = L-4 = 8188 per row, rows = B*M = 4096.
//
// main[k] = net[k] - net[k+1]
// net[j]  = fm(j) + fp(j)
//   fm(j) = (v[j+2] >= 0 || j == OUT) ? 0 : F[j+2] - hs[j+1]
//   fp(j) = (v[j+1] <= 0 || j == 0)   ? 0 : F[j+1] + hs[j]
//   hs(i) = minmod3( D[i], 0.25*(D[i]+D[i+1]), D[i+1] ),  D[i] = F[i+1]-F[i]
//   F[i]  = rho[i] * v[i]
//
// v3: v2 + NONTEMPORAL stores. Inputs (268 MB) nearly fit the 256 MiB LLC;
// the 134 MB write stream was evicting them (FETCH_SIZE == half of inputs).
// nt stores keep the output from allocating in LLC so inputs stay resident.

typedef float vf4 __attribute__((ext_vector_type(4)));

__device__ __forceinline__ float minmod3(float a, float b, float c) {
    float mn = fminf(fminf(a, b), c);
    float mx = fmaxf(fmaxf(a, b), c);
    return (mn < 0.0f) ? fminf(mx, 0.0f) : mn;
}

__global__ __launch_bounds__(256) void advect_kernel(
    const float* __restrict__ rho, const float* __restrict__ v,
    float* __restrict__ out, int L, int OUT, int GP8)
{
    int g = blockIdx.x * blockDim.x + threadIdx.x;   // group of 8 outputs
    if (g >= GP8) return;
    long row = blockIdx.y;
    const float* r  = rho + row * (long)L;
    const float* vp = v   + row * (long)L;
    int k0 = g * 8;
    bool full = (k0 + 8 <= OUT);   // full 8-output group needs F[k0..k0+11]

    // 12-wide halo load: outputs k0..k0+7 need indices k0..k0+11 (float4-aligned)
    float4 ra = *(const float4*)(r  + k0);
    float4 rb = *(const float4*)(r  + k0 + 4);
    float4 va = *(const float4*)(vp + k0);
    float4 vb = *(const float4*)(vp + k0 + 4);
    float4 rc, vc;
    if (full) {
        rc = *(const float4*)(r  + k0 + 8);
        vc = *(const float4*)(vp + k0 + 8);
    } else {
        // tail (k0 = 8184): only 4 outputs valid; duplicate to keep regs finite.
        rc = rb; vc = vb;
    }

    float V[12] = {va.x,va.y,va.z,va.w, vb.x,vb.y,vb.z,vb.w, vc.x,vc.y,vc.z,vc.w};
    float R[12] = {ra.x,ra.y,ra.z,ra.w, rb.x,rb.y,rb.z,rb.w, rc.x,rc.y,rc.z,rc.w};
    float F[12];
#pragma unroll
    for (int i = 0; i < 12; ++i) F[i] = R[i] * V[i];

    // forward differences, shared between adjacent hs
    float D[11];
#pragma unroll
    for (int i = 0; i < 11; ++i) D[i] = F[i+1] - F[i];

    // half-slope hs[i] ~ global index k0+i, i in [0,9]
    float hs[10];
#pragma unroll
    for (int i = 0; i < 10; ++i)
        hs[i] = minmod3(D[i], 0.25f * (D[i] + D[i+1]), D[i+1]);

    // net[j] ~ global index k0+j, j in [0,8]
    float net[9];
#pragma unroll
    for (int j = 0; j < 9; ++j) {
        int gj = k0 + j;
        float fm = (V[j+2] >= 0.0f || gj == OUT) ? 0.0f : (F[j+2] - hs[j+1]);
        float fp = (V[j+1] <= 0.0f || gj == 0)   ? 0.0f : (F[j+1] + hs[j]);
        net[j] = fm + fp;
    }

    float* op = out + row * (long)OUT + k0;
    vf4 o0;
    o0.x = net[0] - net[1];
    o0.y = net[1] - net[2];
    o0.z = net[2] - net[3];
    o0.w = net[3] - net[4];
    __builtin_nontemporal_store(o0, (vf4*)op);
    if (full) {
        vf4 o1;
        o1.x = net[4] - net[5];
        o1.y = net[5] - net[6];
        o1.z = net[6] - net[7];
        o1.w = net[7] - net[8];
        __builtin_nontemporal_store(o1, (vf4*)(op + 4));
    }
}

extern "C" void kernel_launch(void* const* d_in, const int* in_sizes, int n_in,
                              void* d_out, int out_size, void* d_ws, size_t ws_size,
                              hipStream_t stream) {
    const float* rho = (const float*)d_in[0];
    const float* v   = (const float*)d_in[1];
    float* out = (float*)d_out;

    const int L    = 8192;
    const int rows = in_sizes[0] / L;   // B*M = 4096
    const int OUT  = L - 4;             // 8188
    const int GP8  = (OUT + 7) / 8;     // 1024 groups of 8 per row

    dim3 block(256);
    dim3 grid((GP8 + 255) / 256, rows); // (4, 4096)
    hipLaunchKernelGGL(advect_kernel, grid, block, 0, stream,
                       rho, v, out, L, OUT, GP8);
}

// Round 4
// 341.300 us; speedup vs baseline: 1.0467x; 1.0467x over previous
//
#include <hip/hip_runtime.h>

// Advect: minmod-limited flux stencil along last axis.
// L = 8192 (ghost-padded), OUT = L-4 = 8188 per row, rows = B*M = 4096.
//
// main[k] = net[k] - net[k+1]
// net[j]  = fm(j) + fp(j)
//   fm(j) = (v[j+2] >= 0 || j == OUT) ? 0 : F[j+2] - hs[j+1]
//   fp(j) = (v[j+1] <= 0 || j == 0)   ? 0 : F[j+1] + hs[j]
//   hs(i) = minmod3( D[i], 0.25*(D[i]+D[i+1]), D[i+1] ),  D[i] = F[i+1]-F[i]
//   F[i]  = rho[i] * v[i]
//
// v4 (rerun; R3 was an infra failure): v2 + NONTEMPORAL LOADS, plain stores.
//   R2 finding: HBM-effective BW pinned ~2.3 TB/s across configs while copy
//   does 6.3. Theory: inputs (268.4 MB) exactly fill the 256 MiB LLC; write
//   stream evicts ~half; HBM reads become a scattered 64B-granule subset of
//   lines (the evictions) -> DRAM efficiency collapses. nt loads keep inputs
//   OUT of LLC so HBM reads are long sequential streams (copy-like pattern).

typedef float vf4 __attribute__((ext_vector_type(4)));

__device__ __forceinline__ float minmod3(float a, float b, float c) {
    float mn = fminf(fminf(a, b), c);
    float mx = fmaxf(fmaxf(a, b), c);
    return (mn < 0.0f) ? fminf(mx, 0.0f) : mn;
}

__global__ __launch_bounds__(256) void advect_kernel(
    const float* __restrict__ rho, const float* __restrict__ v,
    float* __restrict__ out, int L, int OUT, int GP8)
{
    int g = blockIdx.x * blockDim.x + threadIdx.x;   // group of 8 outputs
    if (g >= GP8) return;
    long row = blockIdx.y;
    const float* r  = rho + row * (long)L;
    const float* vp = v   + row * (long)L;
    int k0 = g * 8;
    bool full = (k0 + 8 <= OUT);   // full 8-output group needs F[k0..k0+11]

    // 12-wide halo load: outputs k0..k0+7 need indices k0..k0+11 (float4-aligned)
    vf4 ra = __builtin_nontemporal_load((const vf4*)(r  + k0));
    vf4 rb = __builtin_nontemporal_load((const vf4*)(r  + k0 + 4));
    vf4 va = __builtin_nontemporal_load((const vf4*)(vp + k0));
    vf4 vb = __builtin_nontemporal_load((const vf4*)(vp + k0 + 4));
    vf4 rc, vc;
    if (full) {
        rc = __builtin_nontemporal_load((const vf4*)(r  + k0 + 8));
        vc = __builtin_nontemporal_load((const vf4*)(vp + k0 + 8));
    } else {
        // tail (k0 = 8184): only 4 outputs valid; duplicate to keep regs finite.
        rc = rb; vc = vb;
    }

    float V[12] = {va.x,va.y,va.z,va.w, vb.x,vb.y,vb.z,vb.w, vc.x,vc.y,vc.z,vc.w};
    float R[12] = {ra.x,ra.y,ra.z,ra.w, rb.x,rb.y,rb.z,rb.w, rc.x,rc.y,rc.z,rc.w};
    float F[12];
#pragma unroll
    for (int i = 0; i < 12; ++i) F[i] = R[i] * V[i];

    // forward differences, shared between adjacent hs
    float D[11];
#pragma unroll
    for (int i = 0; i < 11; ++i) D[i] = F[i+1] - F[i];

    // half-slope hs[i] ~ global index k0+i, i in [0,9]
    float hs[10];
#pragma unroll
    for (int i = 0; i < 10; ++i)
        hs[i] = minmod3(D[i], 0.25f * (D[i] + D[i+1]), D[i+1]);

    // net[j] ~ global index k0+j, j in [0,8]
    float net[9];
#pragma unroll
    for (int j = 0; j < 9; ++j) {
        int gj = k0 + j;
        float fm = (V[j+2] >= 0.0f || gj == OUT) ? 0.0f : (F[j+2] - hs[j+1]);
        float fp = (V[j+1] <= 0.0f || gj == 0)   ? 0.0f : (F[j+1] + hs[j]);
        net[j] = fm + fp;
    }

    float* op = out + row * (long)OUT + k0;
    float4 o0;
    o0.x = net[0] - net[1];
    o0.y = net[1] - net[2];
    o0.z = net[2] - net[3];
    o0.w = net[3] - net[4];
    *(float4*)op = o0;
    if (full) {
        float4 o1;
        o1.x = net[4] - net[5];
        o1.y = net[5] - net[6];
        o1.z = net[6] - net[7];
        o1.w = net[7] - net[8];
        *(float4*)(op + 4) = o1;
    }
}

extern "C" void kernel_launch(void* const* d_in, const int* in_sizes, int n_in,
                              void* d_out, int out_size, void* d_ws, size_t ws_size,
                              hipStream_t stream) {
    const float* rho = (const float*)d_in[0];
    const float* v   = (const float*)d_in[1];
    float* out = (float*)d_out;

    const int L    = 8192;
    const int rows = in_sizes[0] / L;   // B*M = 4096
    const int OUT  = L - 4;             // 8188
    const int GP8  = (OUT + 7) / 8;     // 1024 groups of 8 per row

    dim3 block(256);
    dim3 grid((GP8 + 255) / 256, rows); // (4, 4096)
    hipLaunchKernelGGL(advect_kernel, grid, block, 0, stream,
                       rho, v, out, L, OUT, GP8);
}

// Round 5
// 315.281 us; speedup vs baseline: 1.1331x; 1.0825x over previous
//
#include <hip/hip_runtime.h>

// Advect: minmod-limited flux stencil along last axis.
// L = 8192 (ghost-padded), OUT = L-4 = 8188 per row, rows = B*M = 4096.
//
// main[k] = net[k] - net[k+1]
// net[j]  = fm(j) + fp(j)
//   fm(j) = (v[j+2] >= 0 || j == OUT) ? 0 : F[j+2] - hs[j+1]
//   fp(j) = (v[j+1] <= 0 || j == 0)   ? 0 : F[j+1] + hs[j]
//   hs(i) = 0.5 * minmod3( th*(F[i+1]-F[i]), 0.5*(F[i+2]-F[i]), th*(F[i+2]-F[i+1]) )
//   F[i]  = rho[i] * v[i]
//
// v5: R0 layout (4 outputs/thread, every load & store instruction fully
//     coalesced: 64 lanes x 16B contiguous) + NONTEMPORAL STORES.
//   Rationale: R2's nt-store WRITE amplification (1.8x) was caused by the
//   8/thread layout's 32B-interleaved half-line store instrs defeating the
//   write combiner. With the R0 layout each store instr covers full 64B
//   lines, so nt should be amplification-free while keeping the 134 MB
//   write stream OUT of the LLC -> the 268 MB input set stays resident
//   (R1 showed writes evict ~half of it, FETCH = 132 MB).

#define TH 2.0f

typedef float vf4 __attribute__((ext_vector_type(4)));

__device__ __forceinline__ float minmod3(float a, float b, float c) {
    float mn = fminf(fminf(a, b), c);
    float mx = fmaxf(fmaxf(a, b), c);
    return (mn < 0.0f) ? fminf(mx, 0.0f) : mn;
}

__global__ __launch_bounds__(256) void advect_kernel(
    const float* __restrict__ rho, const float* __restrict__ v,
    float* __restrict__ out, int L, int OUT, int GPR)
{
    int g = blockIdx.x * blockDim.x + threadIdx.x;   // group of 4 outputs
    if (g >= GPR) return;
    long row = blockIdx.y;
    const float* r  = rho + row * (long)L;
    const float* vp = v   + row * (long)L;
    int k0 = g * 4;

    // 8-wide halo load: outputs k0..k0+3 need indices k0..k0+7 (both float4-aligned)
    float4 ra = *(const float4*)(r  + k0);
    float4 rb = *(const float4*)(r  + k0 + 4);
    float4 va = *(const float4*)(vp + k0);
    float4 vb = *(const float4*)(vp + k0 + 4);

    float V[8] = {va.x, va.y, va.z, va.w, vb.x, vb.y, vb.z, vb.w};
    float R[8] = {ra.x, ra.y, ra.z, ra.w, rb.x, rb.y, rb.z, rb.w};
    float F[8];
#pragma unroll
    for (int i = 0; i < 8; ++i) F[i] = R[i] * V[i];

    // half-slope hs[i] ~ global index k0+i, i in [0,5]
    float hs[6];
#pragma unroll
    for (int i = 0; i < 6; ++i) {
        float c0 = TH   * (F[i+1] - F[i]);
        float c1 = 0.5f * (F[i+2] - F[i]);
        float c2 = TH   * (F[i+2] - F[i+1]);
        hs[i] = 0.5f * minmod3(c0, c1, c2);
    }

    // net[j] ~ global index k0+j, j in [0,4]
    float net[5];
#pragma unroll
    for (int j = 0; j < 5; ++j) {
        int gj = k0 + j;
        float fm = (V[j+2] >= 0.0f || gj == OUT) ? 0.0f : (F[j+2] - hs[j+1]);
        float fp = (V[j+1] <= 0.0f || gj == 0)   ? 0.0f : (F[j+1] + hs[j]);
        net[j] = fm + fp;
    }

    vf4 o;
    o.x = net[0] - net[1];
    o.y = net[1] - net[2];
    o.z = net[2] - net[3];
    o.w = net[3] - net[4];
    __builtin_nontemporal_store(o, (vf4*)(out + row * (long)OUT + k0));
}

extern "C" void kernel_launch(void* const* d_in, const int* in_sizes, int n_in,
                              void* d_out, int out_size, void* d_ws, size_t ws_size,
                              hipStream_t stream) {
    const float* rho = (const float*)d_in[0];
    const float* v   = (const float*)d_in[1];
    float* out = (float*)d_out;

    const int L    = 8192;
    const int rows = in_sizes[0] / L;   // B*M = 4096
    const int OUT  = L - 4;             // 8188
    const int GPR  = OUT / 4;           // 2047 float4 groups per row

    dim3 block(256);
    dim3 grid((GPR + 255) / 256, rows); // (8, 4096)
    hipLaunchKernelGGL(advect_kernel, grid, block, 0, stream,
                       rho, v, out, L, OUT, GPR);
}

// Round 6
// 307.231 us; speedup vs baseline: 1.1628x; 1.0262x over previous
//
#include <hip/hip_runtime.h>

// Advect: minmod-limited flux stencil along last axis.
// L = 8192 (ghost-padded), OUT = L-4 = 8188 per row, rows = B*M = 4096.
//
// main[k] = net[k] - net[k+1]
// net[j]  = fm(j) + fp(j)
//   fm(j) = (v[j+2] >= 0 || j == OUT) ? 0 : F[j+2] - hs[j+1]
//   fp(j) = (v[j+1] <= 0 || j == 0)   ? 0 : F[j+1] + hs[j]
//   hs(i) = 0.5 * minmod3( th*(F[i+1]-F[i]), 0.5*(F[i+2]-F[i]), th*(F[i+2]-F[i+1]) )
//   F[i]  = rho[i] * v[i]
//
// v6 = R0 revert (best measured: 107.5 us/dispatch, 3.74 TB/s demand BW).
// Session findings (R1-R5, all counter-verified):
//  - 8/thr tiling (redundancy 1.5x vs 2.0x): neutral-to-worse. Not issue-bound.
//  - nt stores: WRITE amplification 1.8x on interleaved layout (R2); clean on
//    coalesced layout but FETCH unchanged and +16% time (R5). Input ~50% LLC
//    hit rate is CAPACITY (inputs 268.4 MB == 256 MiB LLC), not write-eviction.
//  - nt loads: HBM-side efficiency 2.35->3.27 TB/s but +125 MB refetch, net
//    slower (R4).
//  - Demand BW pinned at ~3.6-3.7 TB/s across all variants => upstream ceiling
//    for this 2R:1W LLC-straddling mix. VALU 18%, occupancy 65-75%, VGPR 16,
//    0 bank conflicts, HBM bytes ideal: nothing else is binding.

#define TH 2.0f

__device__ __forceinline__ float minmod3(float a, float b, float c) {
    float mn = fminf(fminf(a, b), c);
    float mx = fmaxf(fmaxf(a, b), c);
    return (mn < 0.0f) ? fminf(mx, 0.0f) : mn;
}

__global__ __launch_bounds__(256) void advect_kernel(
    const float* __restrict__ rho, const float* __restrict__ v,
    float* __restrict__ out, int L, int OUT, int GPR)
{
    int g = blockIdx.x * blockDim.x + threadIdx.x;   // group of 4 outputs
    if (g >= GPR) return;
    long row = blockIdx.y;
    const float* r  = rho + row * (long)L;
    const float* vp = v   + row * (long)L;
    int k0 = g * 4;

    // 8-wide halo load: outputs k0..k0+3 need indices k0..k0+7 (both float4-aligned)
    float4 ra = *(const float4*)(r  + k0);
    float4 rb = *(const float4*)(r  + k0 + 4);
    float4 va = *(const float4*)(vp + k0);
    float4 vb = *(const float4*)(vp + k0 + 4);

    float V[8] = {va.x, va.y, va.z, va.w, vb.x, vb.y, vb.z, vb.w};
    float R[8] = {ra.x, ra.y, ra.z, ra.w, rb.x, rb.y, rb.z, rb.w};
    float F[8];
#pragma unroll
    for (int i = 0; i < 8; ++i) F[i] = R[i] * V[i];

    // half-slope hs[i] ~ global index k0+i, i in [0,5]
    float hs[6];
#pragma unroll
    for (int i = 0; i < 6; ++i) {
        float c0 = TH   * (F[i+1] - F[i]);
        float c1 = 0.5f * (F[i+2] - F[i]);
        float c2 = TH   * (F[i+2] - F[i+1]);
        hs[i] = 0.5f * minmod3(c0, c1, c2);
    }

    // net[j] ~ global index k0+j, j in [0,4]
    float net[5];
#pragma unroll
    for (int j = 0; j < 5; ++j) {
        int gj = k0 + j;
        float fm = (V[j+2] >= 0.0f || gj == OUT) ? 0.0f : (F[j+2] - hs[j+1]);
        float fp = (V[j+1] <= 0.0f || gj == 0)   ? 0.0f : (F[j+1] + hs[j]);
        net[j] = fm + fp;
    }

    float4 o;
    o.x = net[0] - net[1];
    o.y = net[1] - net[2];
    o.z = net[2] - net[3];
    o.w = net[3] - net[4];
    *(float4*)(out + row * (long)OUT + k0) = o;
}

extern "C" void kernel_launch(void* const* d_in, const int* in_sizes, int n_in,
                              void* d_out, int out_size, void* d_ws, size_t ws_size,
                              hipStream_t stream) {
    const float* rho = (const float*)d_in[0];
    const float* v   = (const float*)d_in[1];
    float* out = (float*)d_out;

    const int L    = 8192;
    const int rows = in_sizes[0] / L;   // B*M = 4096
    const int OUT  = L - 4;             // 8188
    const int GPR  = OUT / 4;           // 2047 float4 groups per row

    dim3 block(256);
    dim3 grid((GPR + 255) / 256, rows); // (8, 4096)
    hipLaunchKernelGGL(advect_kernel, grid, block, 0, stream,
                       rho, v, out, L, OUT, GPR);
}